// Round 13
// baseline (305.011 us; speedup 1.0000x reference)
//
#include <hip/hip_runtime.h>

// RNN-T joint: log_softmax(fc2(tanh(fc1(cat(enc,dec))))), fused.
// B=4, M=256, N=128, D=512, C=1024, JOINT=1024.
// ws: heb f32 [1024][512] (he+b1) | hdb bf16 [512][512] | w2p i8 512KB | scF f32[1024]
//
// R13 = R12 int8 pipeline with 64-row x 16-wave blocks: halves the dominant
// L2 B-feed (each block reads w2p once per 64 rows instead of 32). acc still
// 64 AGPR/lane (64 rows x 64 classes per wave). A-prefetch deepened to 4
// slots (covers ~200cy L2 latency; same 32 VGPR as R12's aw[2][4]).

typedef __attribute__((ext_vector_type(8))) __bf16 bf16x8;
typedef __attribute__((ext_vector_type(8))) unsigned short u16x8;
typedef __attribute__((ext_vector_type(4))) float f32x4;
typedef __attribute__((ext_vector_type(4))) int i32x4;
typedef __attribute__((ext_vector_type(16))) int i32x16;

__device__ __forceinline__ float tanh_fast(float x) {
    float e = __expf(2.0f * x);
    return 1.0f - 2.0f / (e + 1.0f);
}
__device__ __forceinline__ float bf2f(unsigned short u) {
    return __builtin_bit_cast(float, (unsigned)u << 16);
}
__device__ __forceinline__ unsigned short f2bf(float f) {
    return __builtin_bit_cast(unsigned short, (__bf16)f);
}
__device__ __forceinline__ int pack4(float a, float b, float c, float d, float s) {
    int q0 = __float2int_rn(a * s) & 255;
    int q1 = __float2int_rn(b * s) & 255;
    int q2 = __float2int_rn(c * s) & 255;
    int q3 = __float2int_rn(d * s) & 255;
    return q0 | (q1 << 8) | (q2 << 16) | (q3 << 24);
}

// k_prep-only LDS swizzle
__device__ __forceinline__ int swz(int row, int kbyte) {
    return row * 1024 + (kbyte ^ ((row & 7) << 4));
}

__device__ __forceinline__ bf16x8 cvt8(float4 a, float4 b) {
    bf16x8 r;
    r[0] = (__bf16)a.x; r[1] = (__bf16)a.y; r[2] = (__bf16)a.z; r[3] = (__bf16)a.w;
    r[4] = (__bf16)b.x; r[5] = (__bf16)b.y; r[6] = (__bf16)b.z; r[7] = (__bf16)b.w;
    return r;
}

// ---------------------------------------------------------------------------
// Prep (validated R12): blocks 0..31 -> heb = enc@w1enc^T + b1 (f32, 32 rows),
// 32..47 -> hdb = bf16(dec@w1dec^T), 48..63 -> w2 quantize+pack (i8) + scF.
// w2p chunk for (class c, kt32 t): region ((c>>5)*16 + t)*1024, byte
// lh*512 + (c&31)*16; consumer lane l = lh*32 + (c&31) reads l*16.
// ---------------------------------------------------------------------------
__global__ __launch_bounds__(512) void k_prep(
    const float* __restrict__ enc, const float* __restrict__ dec,
    const float* __restrict__ w1, const float* __restrict__ b1,
    const float* __restrict__ w2,
    float* __restrict__ heb, unsigned short* __restrict__ hdb,
    char* __restrict__ w2p, float* __restrict__ scF)
{
    const int bid = blockIdx.x, tid = threadIdx.x;
    const int lane = tid & 63, wid = tid >> 6;

    if (bid >= 48) {  // quantize + pack w2 -> w2p (i8), write scF
        int W = (bid - 48) * 8 + wid;            // 0..127
        #pragma unroll
        for (int j = 0; j < 8; ++j) {
            int c = W * 8 + j;
            const float4* s = (const float4*)(w2 + c * 512 + lane * 8);
            float4 a = s[0], bq = s[1];
            float m = fmaxf(fmaxf(fabsf(a.x), fabsf(a.y)), fmaxf(fabsf(a.z), fabsf(a.w)));
            m = fmaxf(m, fmaxf(fmaxf(fabsf(bq.x), fabsf(bq.y)),
                               fmaxf(fabsf(bq.z), fabsf(bq.w))));
            #pragma unroll
            for (int d = 1; d < 64; d <<= 1) m = fmaxf(m, __shfl_xor(m, d));
            float r = 127.f / m;
            int d0 = pack4(a.x, a.y, a.z, a.w, r);
            int d1 = pack4(bq.x, bq.y, bq.z, bq.w, r);
            int t = lane >> 2, lhc = (lane >> 1) & 1, off = lane & 1;
            char* dst = w2p + ((size_t)((c >> 5) * 16 + t)) * 1024
                        + lhc * 512 + (c & 31) * 16 + off * 8;
            *(unsigned long long*)dst =
                (unsigned)d0 | ((unsigned long long)(unsigned)d1 << 32);
            if (lane == 0) scF[c] = m / 16129.f;   // 127*127
        }
        return;
    }

    __shared__ uint4 ldsq[2048];           // 32 KB A tile (32 rows x 512 k bf16)
    char* lds = (char*)ldsq;

    const bool ishe = bid < 32;
    const int r0 = (ishe ? bid : bid - 32) * 32;
    const float* src = (ishe ? enc : dec) + r0 * 512;
    const float* wsrc = w1 + (ishe ? 0 : 512);

    #pragma unroll
    for (int j = 0; j < 4; j++) {
        int row = wid * 4 + j;
        const float4* p = (const float4*)(src + row * 512 + lane * 8);
        *(bf16x8*)(lds + swz(row, lane * 16)) = cvt8(p[0], p[1]);
    }
    __syncthreads();

    const int lr = lane & 15, lg = lane >> 4;
    f32x4 acc[2][4];
    #pragma unroll
    for (int rt = 0; rt < 2; rt++)
        #pragma unroll
        for (int ct = 0; ct < 4; ct++)
            acc[rt][ct] = f32x4{0.f, 0.f, 0.f, 0.f};

    #pragma unroll 1
    for (int ks = 0; ks < 512; ks += 32) {
        bf16x8 af[2];
        #pragma unroll
        for (int rt = 0; rt < 2; rt++)
            af[rt] = *(const bf16x8*)(lds + swz(rt * 16 + lr, ks * 2 + lg * 16));
        #pragma unroll
        for (int ct = 0; ct < 4; ct++) {
            int col = wid * 64 + ct * 16 + lr;
            const float4* wp = (const float4*)(wsrc + col * 1024 + ks + lg * 8);
            bf16x8 bfr = cvt8(wp[0], wp[1]);
            #pragma unroll
            for (int rt = 0; rt < 2; rt++)
                acc[rt][ct] = __builtin_amdgcn_mfma_f32_16x16x32_bf16(af[rt], bfr, acc[rt][ct], 0, 0, 0);
        }
    }

    if (ishe) {
        float b1v[4];
        #pragma unroll
        for (int ct = 0; ct < 4; ct++) b1v[ct] = b1[wid * 64 + ct * 16 + lr];
        #pragma unroll
        for (int rt = 0; rt < 2; rt++)
            #pragma unroll
            for (int ct = 0; ct < 4; ct++)
                #pragma unroll
                for (int reg = 0; reg < 4; reg++)
                    heb[(r0 + rt * 16 + lg * 4 + reg) * 512 + wid * 64 + ct * 16 + lr] =
                        acc[rt][ct][reg] + b1v[ct];
    } else {
        #pragma unroll
        for (int rt = 0; rt < 2; rt++)
            #pragma unroll
            for (int ct = 0; ct < 4; ct++)
                #pragma unroll
                for (int reg = 0; reg < 4; reg++)
                    hdb[(r0 + rt * 16 + lg * 4 + reg) * 512 + wid * 64 + ct * 16 + lr] =
                        f2bf(acc[rt][ct][reg]);
    }
}

// ---------------------------------------------------------------------------
// Main: block = 64 rows (one (b,m), 64 n's) x 1024 classes, 16 waves.
// mfma_i32_32x32x32_i8 swapped: wave w owns classes [w*64, w*64+64) for
// row-tiles rt in {0,1} -> acc[2][2] i32x16 = 64 AGPR/lane. Lane holds
// row n = rt*32 + (lane&31); classes w*64 + ct*32 + 8q + 4*(lane>>5) + i.
// 4-deep A slot-reuse prefetch. hid_q 32 KB LDS; transpose epilogue;
// full-line nt stores; XCD swizzle.
// ---------------------------------------------------------------------------
__global__ __launch_bounds__(1024, 4) void k_main(
    const float* __restrict__ heb, const unsigned short* __restrict__ hdb,
    const float* __restrict__ b2, const char* __restrict__ w2p,
    const float* __restrict__ scF, float* __restrict__ out)
{
    __shared__ uint4 hidq[2048];          // 32 KB: regions (rt*16+t)*1KB
    __shared__ uint4 trans[4096];         // 64 KB: 4 KB per wave
    __shared__ float redm[64][16];
    __shared__ float reds[64][16];
    char* hid = (char*)hidq;

    // XCD-bijective remap (2048 % 8 == 0): 256 consecutive items per XCD.
    const int item = ((blockIdx.x & 7) << 8) | (blockIdx.x >> 3);
    const int tid = threadIdx.x;
    const int bm = item >> 1, n0 = (item & 1) << 6;
    const int b = bm >> 8;
    const int lane = tid & 63, w = tid >> 6;
    const int l5 = lane & 31, lh = lane >> 5;

    // ---- stage hid_q = i8(tanh(heb + hd) * 127): wave w -> regions 2w, 2w+1 ----
    {
        const float* ep = heb + (size_t)bm * 512;
        #pragma unroll
        for (int it = 0; it < 2; ++it) {
            int R = w * 2 + it;              // region = rt*16 + t
            int rt = R >> 4, t = R & 15;
            int k0 = t * 32 + lh * 16;
            const unsigned short* hb =
                hdb + (size_t)(b * 128 + n0 + rt * 32 + l5) * 512 + k0;
            u16x8 hv0 = *(const u16x8*)(hb);
            u16x8 hv1 = *(const u16x8*)(hb + 8);
            float4 e0 = *(const float4*)(ep + k0);
            float4 e1 = *(const float4*)(ep + k0 + 4);
            float4 e2 = *(const float4*)(ep + k0 + 8);
            float4 e3 = *(const float4*)(ep + k0 + 12);
            i32x4 o;
            o[0] = pack4(tanh_fast(bf2f(hv0[0]) + e0.x), tanh_fast(bf2f(hv0[1]) + e0.y),
                         tanh_fast(bf2f(hv0[2]) + e0.z), tanh_fast(bf2f(hv0[3]) + e0.w), 127.f);
            o[1] = pack4(tanh_fast(bf2f(hv0[4]) + e1.x), tanh_fast(bf2f(hv0[5]) + e1.y),
                         tanh_fast(bf2f(hv0[6]) + e1.z), tanh_fast(bf2f(hv0[7]) + e1.w), 127.f);
            o[2] = pack4(tanh_fast(bf2f(hv1[0]) + e2.x), tanh_fast(bf2f(hv1[1]) + e2.y),
                         tanh_fast(bf2f(hv1[2]) + e2.z), tanh_fast(bf2f(hv1[3]) + e2.w), 127.f);
            o[3] = pack4(tanh_fast(bf2f(hv1[4]) + e3.x), tanh_fast(bf2f(hv1[5]) + e3.y),
                         tanh_fast(bf2f(hv1[6]) + e3.z), tanh_fast(bf2f(hv1[7]) + e3.w), 127.f);
            *(i32x4*)(hid + R * 1024 + lane * 16) = o;
        }
    }
    __syncthreads();

    // ---- K-loop: w2 (A) from L2, 4-deep slot-reuse prefetch; hid_q (B) LDS ----
    // A-chunk (ctile = w*2+ct, t) at byte (ctile*16 + t)*1024 + lane*16
    const char* pw = w2p + ((size_t)w << 15) + (lane << 4);
    const char* la = hid + (lane << 4);

    i32x16 acc[2][2];
    #pragma unroll
    for (int rt = 0; rt < 2; rt++)
        #pragma unroll
        for (int ct = 0; ct < 2; ct++)
            #pragma unroll
            for (int r = 0; r < 16; r++)
                acc[rt][ct][r] = 0;

    i32x4 aw[4][2];
    #pragma unroll
    for (int s = 0; s < 4; s++)
        #pragma unroll
        for (int ct = 0; ct < 2; ct++)
            aw[s][ct] = *(const i32x4*)(pw + ct * 16384 + s * 1024);

    i32x4 h0[2];
    #pragma unroll
    for (int rt = 0; rt < 2; rt++)
        h0[rt] = *(const i32x4*)(la + rt * 16384);

    #pragma unroll
    for (int kt = 0; kt < 16; ++kt) {
        i32x4 hn[2];
        if (kt < 15) {
            #pragma unroll
            for (int rt = 0; rt < 2; rt++)
                hn[rt] = *(const i32x4*)(la + rt * 16384 + (kt + 1) * 1024);
        }
        __builtin_amdgcn_s_setprio(1);
        #pragma unroll
        for (int ct = 0; ct < 2; ct++)
            #pragma unroll
            for (int rt = 0; rt < 2; rt++)
                acc[rt][ct] = __builtin_amdgcn_mfma_i32_32x32x32_i8(
                    aw[kt & 3][ct], h0[rt], acc[rt][ct], 0, 0, 0);
        __builtin_amdgcn_s_setprio(0);
        if (kt < 12) {
            #pragma unroll
            for (int ct = 0; ct < 2; ct++)
                aw[kt & 3][ct] = *(const i32x4*)(pw + ct * 16384 + (kt + 4) * 1024);
        }
        h0[0] = hn[0]; h0[1] = hn[1];
    }

    // ---- dequant + b2 (classes independent of rt) ----
    #pragma unroll
    for (int ct = 0; ct < 2; ct++)
        #pragma unroll
        for (int q = 0; q < 4; q++) {
            const int base = w * 64 + ct * 32 + q * 8 + lh * 4;
            float4 sc4 = *(const float4*)(scF + base);
            float4 b24 = *(const float4*)(b2 + base);
            #pragma unroll
            for (int rt = 0; rt < 2; rt++) {
                acc[rt][ct][q * 4 + 0] = __float_as_int((float)acc[rt][ct][q * 4 + 0] * sc4.x + b24.x);
                acc[rt][ct][q * 4 + 1] = __float_as_int((float)acc[rt][ct][q * 4 + 1] * sc4.y + b24.y);
                acc[rt][ct][q * 4 + 2] = __float_as_int((float)acc[rt][ct][q * 4 + 2] * sc4.z + b24.z);
                acc[rt][ct][q * 4 + 3] = __float_as_int((float)acc[rt][ct][q * 4 + 3] * sc4.w + b24.w);
            }
        }

    // ---- row stats per rt: 32 values in-lane, merge lane^32 ----
    #pragma unroll
    for (int rt = 0; rt < 2; rt++) {
        float mx = -3.4e38f;
        #pragma unroll
        for (int ct = 0; ct < 2; ct++)
            #pragma unroll
            for (int r = 0; r < 16; r++)
                mx = fmaxf(mx, __int_as_float(acc[rt][ct][r]));
        float sv = 0.f;
        #pragma unroll
        for (int ct = 0; ct < 2; ct++)
            #pragma unroll
            for (int r = 0; r < 16; r++)
                sv += __expf(__int_as_float(acc[rt][ct][r]) - mx);
        float mo = __shfl_xor(mx, 32), so = __shfl_xor(sv, 32);
        float mn = fmaxf(mx, mo);
        sv = sv * __expf(mx - mn) + so * __expf(mo - mn);
        mx = mn;
        if (lh == 0) {
            redm[rt * 32 + l5][w] = mx;
            reds[rt * 32 + l5][w] = sv;
        }
    }
    __syncthreads();

    // ---- combine 16 wave-partials -> logZ per row (per rt) ----
    float logZ[2];
    #pragma unroll
    for (int rt = 0; rt < 2; rt++) {
        int r = rt * 32 + l5;
        const float4* mp = (const float4*)&redm[r][0];
        const float4* sp = (const float4*)&reds[r][0];
        float M;
        {
            float4 m0 = mp[0], m1 = mp[1], m2 = mp[2], m3 = mp[3];
            float a0 = fmaxf(fmaxf(m0.x, m0.y), fmaxf(m0.z, m0.w));
            float a1 = fmaxf(fmaxf(m1.x, m1.y), fmaxf(m1.z, m1.w));
            float a2 = fmaxf(fmaxf(m2.x, m2.y), fmaxf(m2.z, m2.w));
            float a3 = fmaxf(fmaxf(m3.x, m3.y), fmaxf(m3.z, m3.w));
            M = fmaxf(fmaxf(a0, a1), fmaxf(a2, a3));
        }
        float S = 0.f;
        #pragma unroll
        for (int q = 0; q < 4; q++) {
            float4 mq = mp[q], sq = sp[q];
            S += sq.x * __expf(mq.x - M) + sq.y * __expf(mq.y - M)
               + sq.z * __expf(mq.z - M) + sq.w * __expf(mq.w - M);
        }
        logZ[rt] = M + __logf(S);
    }

    // ---- store epilogue: per-wave LDS transpose -> full-line nt stores ----
    char* myr = (char*)trans + w * 4096;
    const size_t rowbase = (size_t)bm * 128 + n0;
    const int rr = lane >> 2, c4 = lane & 3;
    #pragma unroll
    for (int rt = 0; rt < 2; rt++)
        #pragma unroll
        for (int ct = 0; ct < 2; ct++) {
            #pragma unroll
            for (int q = 0; q < 4; q++) {
                f32x4 o;
                o[0] = __int_as_float(acc[rt][ct][q * 4 + 0]) - logZ[rt];
                o[1] = __int_as_float(acc[rt][ct][q * 4 + 1]) - logZ[rt];
                o[2] = __int_as_float(acc[rt][ct][q * 4 + 2]) - logZ[rt];
                o[3] = __int_as_float(acc[rt][ct][q * 4 + 3]) - logZ[rt];
                *(f32x4*)(myr + l5 * 128 + ((q * 32 + lh * 16) ^ ((l5 & 7) << 4))) = o;
            }
            #pragma unroll
            for (int rh = 0; rh < 2; rh++)
                #pragma unroll
                for (int chv = 0; chv < 2; chv++) {
                    int row = rh * 16 + rr;
                    f32x4 v = *(const f32x4*)(myr + row * 128 +
                                              ((chv * 64 + c4 * 16) ^ ((row & 7) << 4)));
                    __builtin_nontemporal_store(v,
                        (f32x4*)(out + (rowbase + rt * 32 + row) * 1024 + w * 64 +
                                 ct * 32 + chv * 16 + c4 * 4));
                }
        }
}

extern "C" void kernel_launch(void* const* d_in, const int* in_sizes, int n_in,
                              void* d_out, int out_size, void* d_ws, size_t ws_size,
                              hipStream_t stream) {
    const float* enc = (const float*)d_in[0];
    const float* dec = (const float*)d_in[1];
    const float* w1  = (const float*)d_in[2];
    const float* b1  = (const float*)d_in[3];
    const float* w2  = (const float*)d_in[4];
    const float* b2  = (const float*)d_in[5];

    float* heb = (float*)d_ws;                                   // 2 MB
    unsigned short* hdb = (unsigned short*)(heb + 1024 * 512);   // 0.5 MB
    char* w2p = (char*)(hdb + 512 * 512);                        // 512 KB
    float* scF = (float*)(w2p + 512 * 1024);                     // 4 KB

    k_prep<<<64, 512, 0, stream>>>(enc, dec, w1, b1, w2, heb, hdb, w2p, scF);
    k_main<<<2048, 1024, 0, stream>>>(heb, hdb, b2, w2p, scF, (float*)d_out);
}